// Round 8
// baseline (154.829 us; speedup 1.0000x reference)
//
#include <hip/hip_runtime.h>
#include <hip/hip_bf16.h>

#define NEG_SLOPE 0.2f
#define EPB 4096   // edges per block in bucket_scatter (256 thr x 16)
#define NHB 64     // hist blocks

typedef __attribute__((ext_vector_type(8))) short short8v;   // 8 bf16 bit-patterns
typedef __attribute__((ext_vector_type(4))) float f32x4;

__device__ inline float blo(unsigned u) { return __uint_as_float(u << 16); }
__device__ inline float bhi(unsigned u) { return __uint_as_float(u & 0xffff0000u); }
__device__ inline unsigned short bf16bits(float f) {
    __hip_bfloat16 b = __float2bfloat16(f);
    return *(unsigned short*)&b;
}
__device__ inline unsigned pack2bf(float e, float o) {
    return ((unsigned)bf16bits(o) << 16) | (unsigned)bf16bits(e);
}

// ---------------------------------------------------------------------------
// Shared NT pieces: sBt staging (augmented W^T: cols 0..63 = W_src^T,
// col 64 = W_src@a_src, col 65 = W_dst@a_dst, 66..79 = 0) and the
// 64-row x 80-col MFMA body reading sX/sBt from LDS.
// ---------------------------------------------------------------------------
template <int K>
__device__ inline void stage_sBt(unsigned short* sBt,
                                 const float* __restrict__ W_src,
                                 const float* __restrict__ a_src,
                                 const float* __restrict__ W_dst,
                                 const float* __restrict__ a_dst, int tid) {
    constexpr int PAD = K + 8;
    for (int i = tid; i < 64 * K; i += 256) {
        int k = i >> 6, j = i & 63;
        sBt[j * PAD + k] = bf16bits(W_src[i]);
    }
    for (int i = tid; i < 2 * K; i += 256) {
        int which = (i >= K) ? 1 : 0;
        int k = i - which * K;
        const float* Wr = (which ? W_dst : W_src) + k * 64;
        const float* av = which ? a_dst : a_src;
        float s = 0.f;
        #pragma unroll
        for (int j = 0; j < 64; ++j) s += Wr[j] * av[j];
        sBt[(64 + which) * PAD + k] = bf16bits(s);
    }
    for (int i = tid; i < 14 * K; i += 256) {
        int j = 66 + i / K, k = i % K;
        sBt[j * PAD + k] = 0;
    }
}

template <int K>
__device__ inline void nt_mfma_body(const unsigned short* sBt,
                                    const unsigned short* sX,
                                    int rowblockbase,
                                    unsigned* __restrict__ hb_out,
                                    float* __restrict__ alpha_src,
                                    float* __restrict__ alpha_dst,
                                    int N, int tid) {
    constexpr int PAD = K + 8;
    int wid = tid >> 6, l = tid & 63;
    int jcol = l & 15;

    f32x4 acc[5];
    #pragma unroll
    for (int t = 0; t < 5; ++t) acc[t] = (f32x4){0.f, 0.f, 0.f, 0.f};

    const unsigned short* xrow = &sX[(wid * 16 + (l & 15)) * PAD + (l >> 4) * 8];
    #pragma unroll
    for (int kt = 0; kt < K / 32; ++kt) {
        short8v a = *(const short8v*)(xrow + kt * 32);
        int kbase = kt * 32 + (l >> 4) * 8;
        #pragma unroll
        for (int t = 0; t < 5; ++t) {
            short8v b = *(const short8v*)&sBt[(t * 16 + jcol) * PAD + kbase];
            acc[t] = __builtin_amdgcn_mfma_f32_16x16x32_bf16(a, b, acc[t], 0, 0, 0);
        }
    }

    // C layout: col = l&15 (tile t -> col t*16+jcol), row = (l>>4)*4 + reg
    int rbase = rowblockbase + wid * 16 + (l >> 4) * 4;
    #pragma unroll
    for (int t = 0; t < 4; ++t) {
        #pragma unroll
        for (int r = 0; r < 4; ++r) {
            float v = acc[t][r];
            float w = __shfl_xor(v, 1);
            int row = rbase + r;
            if (!(l & 1) && row < N)
                hb_out[(size_t)row * 32 + t * 8 + (jcol >> 1)] = pack2bf(v, w);
        }
    }
    #pragma unroll
    for (int r = 0; r < 4; ++r) {
        int row = rbase + r;
        if (row < N) {
            if (jcol == 0) alpha_src[row] = acc[4][r];
            if (jcol == 1) alpha_dst[row] = acc[4][r];
        }
    }
}

// ---------------------------------------------------------------------------
// Dispatch 1: NT layer-1 (blocks [0, ntb)) fused with bucket histogram
// partial counts (blocks [ntb, ntb+NHB)). Independent work, one dispatch.
// ---------------------------------------------------------------------------
__global__ __launch_bounds__(256) void fused_nt1_hist(
    const float* __restrict__ x,        // [N][128]
    const float* __restrict__ W_src, const float* __restrict__ a_src,
    const float* __restrict__ W_dst, const float* __restrict__ a_dst,
    unsigned* __restrict__ hb_out, float* __restrict__ alpha_src,
    float* __restrict__ alpha_dst, int N,
    const int* __restrict__ dst, int* __restrict__ partials, int E, int ntb) {
    constexpr int K = 128, PAD = K + 8;
    __shared__ unsigned short sBt[80 * PAD];
    __shared__ unsigned short sX[64 * PAD];
    __shared__ int lh[256];
    int tid = threadIdx.x;

    if ((int)blockIdx.x >= ntb) {
        // ---- histogram partial counts (no global atomics, no init pass) ----
        int bh = blockIdx.x - ntb;
        lh[tid] = 0;
        __syncthreads();
        for (int e = bh * 256 + tid; e < E; e += NHB * 256)
            atomicAdd(&lh[dst[e] >> 8], 1);
        __syncthreads();
        partials[bh * 256 + tid] = lh[tid];
        return;
    }

    // ---- NT layer 1 ----
    stage_sBt<K>(sBt, W_src, a_src, W_dst, a_dst, tid);
    for (int idx = tid; idx < 64 * K / 4; idx += 256) {
        int row = (idx * 4) / K, col = (idx * 4) % K;
        int g = blockIdx.x * 64 + row;
        const float4 f = *(const float4*)(x + (size_t)((g < N) ? g : N - 1) * K + col);
        unsigned short* d = &sX[row * PAD + col];
        d[0] = bf16bits(f.x); d[1] = bf16bits(f.y);
        d[2] = bf16bits(f.z); d[3] = bf16bits(f.w);
    }
    __syncthreads();
    nt_mfma_body<K>(sBt, sX, blockIdx.x * 64, hb_out, alpha_src, alpha_dst, N, tid);
}

// ---------------------------------------------------------------------------
// Dispatch 2: reduce hist partials -> exclusive scan -> bases/cursors
// ---------------------------------------------------------------------------
__global__ __launch_bounds__(256) void bucket_scan(const int* __restrict__ partials,
                                                   int* __restrict__ bucket_base,
                                                   int* __restrict__ bucket_cursor) {
    __shared__ int tmp[256];
    int tid = threadIdx.x;
    int v = 0;
    #pragma unroll 8
    for (int b = 0; b < NHB; ++b) v += partials[b * 256 + tid];
    tmp[tid] = v;
    __syncthreads();
    for (int off = 1; off < 256; off <<= 1) {
        int t = (tid >= off) ? tmp[tid - off] : 0;
        __syncthreads();
        tmp[tid] += t;
        __syncthreads();
    }
    int excl = tmp[tid] - v;
    bucket_base[tid] = excl;
    bucket_cursor[tid] = excl;
    if (tid == 255) bucket_base[256] = tmp[255];   // == E
}

// ---------------------------------------------------------------------------
// Dispatch 3: scatter edges into bucket-dense runs (block reservation).
// ebuf entry = (dst&255)<<16 | src   (requires N <= 65536)
// ---------------------------------------------------------------------------
__global__ __launch_bounds__(256) void bucket_scatter(const int* __restrict__ src,
                                                      const int* __restrict__ dst,
                                                      int* __restrict__ bucket_cursor,
                                                      unsigned* __restrict__ ebuf, int E) {
    __shared__ int lhist[256];
    __shared__ int lbase[256];
    int tid = threadIdx.x;
    lhist[tid] = 0;
    __syncthreads();
    int base = blockIdx.x * EPB;
    int bkt[16], rank[16];
    unsigned pack[16];
    #pragma unroll
    for (int i = 0; i < 16; ++i) {
        int e = base + i * 256 + tid;
        bkt[i] = -1;
        if (e < E) {
            int d = dst[e], s = src[e];
            bkt[i]  = d >> 8;
            pack[i] = ((unsigned)(d & 255) << 16) | (unsigned)s;
            rank[i] = atomicAdd(&lhist[bkt[i]], 1);
        }
    }
    __syncthreads();
    int cnt = lhist[tid];
    if (cnt) lbase[tid] = atomicAdd(&bucket_cursor[tid], cnt);
    __syncthreads();
    #pragma unroll
    for (int i = 0; i < 16; ++i)
        if (bkt[i] >= 0) ebuf[lbase[bkt[i]] + rank[i]] = pack[i];
}

// ---------------------------------------------------------------------------
// Dispatch 4: per bucket, row_ptr + csr_src within its contiguous run.
// ---------------------------------------------------------------------------
__global__ __launch_bounds__(256) void bucket_build(const unsigned* __restrict__ ebuf,
                                                    const int* __restrict__ bucket_base,
                                                    int* __restrict__ row_ptr,
                                                    int* __restrict__ csr_src,
                                                    int N, int E) {
    __shared__ int deg[256];
    __shared__ int cur[256];
    __shared__ int tmp[256];
    int b = blockIdx.x, tid = threadIdx.x;
    int ebase = bucket_base[b], eend = bucket_base[b + 1];
    deg[tid] = 0;
    __syncthreads();
    for (int e = ebase + tid; e < eend; e += 256)
        atomicAdd(&deg[ebuf[e] >> 16], 1);
    __syncthreads();
    int v = deg[tid];
    tmp[tid] = v;
    __syncthreads();
    for (int off = 1; off < 256; off <<= 1) {
        int t = (tid >= off) ? tmp[tid - off] : 0;
        __syncthreads();
        tmp[tid] += t;
        __syncthreads();
    }
    int excl = tmp[tid] - v;
    int node = b * 256 + tid;
    if (node < N) row_ptr[node] = ebase + excl;
    if (b == 0 && tid == 0) row_ptr[N] = E;
    cur[tid] = excl;
    __syncthreads();
    for (int e = ebase + tid; e < eend; e += 256) {
        unsigned pk = ebuf[e];
        int r = atomicAdd(&cur[pk >> 16], 1);
        csr_src[ebase + r] = (int)(pk & 0xFFFFu);
    }
}

// ---------------------------------------------------------------------------
// Aggregation core for one node (wave-wide). Direct-exp softmax (logits O(10),
// fp32-exp safe, ratio identical to max-subtracted form). Logit phase
// lane = edge; gather phase half-wave per edge, lane = u32 (2 bf16 feats).
// Lanes >= cnt carry p=0,s=0 -> 16-edge groups need no tail guards.
// Returns this lane's output feature value (feature = lane), incl. tanh+bias.
// ---------------------------------------------------------------------------
__device__ inline float agg_node(int node, const int* __restrict__ row_ptr,
                                 const int* __restrict__ csr_src,
                                 const float* __restrict__ alpha_src,
                                 const float* __restrict__ alpha_dst,
                                 const unsigned* __restrict__ hb,
                                 float blane, int lane) {
    int beg = row_ptr[node], end = row_ptr[node + 1];
    float adst = alpha_dst[node];
    int half = lane >> 5, sub = lane & 31;

    float dL = 0.f;
    float aA[4] = {0.f, 0.f, 0.f, 0.f};
    float aB[4] = {0.f, 0.f, 0.f, 0.f};

    for (int c = beg; c < end; c += 64) {
        int cnt = end - c;
        cnt = (cnt < 64) ? cnt : 64;

        int s = 0;
        float p = 0.f;
        if (lane < cnt) {
            s = csr_src[c + lane];
            float t = alpha_src[s] + adst;
            t = (t > 0.f) ? t : NEG_SLOPE * t;
            p = __expf(fminf(t, 60.f));
            dL += p;
        }

        for (int j = 0; j < cnt; j += 16) {
            int   sv[8];
            float pv[8];
            unsigned uv[8];
            #pragma unroll
            for (int i = 0; i < 8; ++i) {
                int e = j + 2 * i + half;
                sv[i] = __shfl(s, e);
                pv[i] = __shfl(p, e);
            }
            #pragma unroll
            for (int i = 0; i < 8; ++i)
                uv[i] = hb[(size_t)sv[i] * 32 + sub];
            #pragma unroll
            for (int i = 0; i < 8; ++i) {
                aA[i & 3] = fmaf(pv[i], blo(uv[i]), aA[i & 3]);
                aB[i & 3] = fmaf(pv[i], bhi(uv[i]), aB[i & 3]);
            }
        }
    }
    float denom = dL;
    #pragma unroll
    for (int off = 32; off; off >>= 1) denom += __shfl_xor(denom, off);

    float accA = (aA[0] + aA[1]) + (aA[2] + aA[3]);
    float accB = (aB[0] + aB[1]) + (aB[2] + aB[3]);
    accA += __shfl_xor(accA, 32);
    accB += __shfl_xor(accB, 32);
    int srcl = lane >> 1;
    float vA = __shfl(accA, srcl);
    float vB = __shfl(accB, srcl);
    float val = (lane & 1) ? vB : vA;
    float r = (denom > 0.f) ? (val / denom) : 0.f;
    return tanhf(r + blane);
}

// ---------------------------------------------------------------------------
// Dispatch 5: agg layer-1 fused with NT layer-2. Block owns 64 dst nodes;
// each wave aggregates 16 of them, writing tanh'd h1 rows (bf16) directly
// into the LDS A-tile; then the 64x80 MFMA produces h2/alpha2. No h1
// global round-trip.
// ---------------------------------------------------------------------------
__global__ __launch_bounds__(256) void fused_agg_nt(
    const int* __restrict__ row_ptr, const int* __restrict__ csr_src,
    const float* __restrict__ alpha_src1, const float* __restrict__ alpha_dst1,
    const unsigned* __restrict__ hb1,   // layer-1 h, packed bf16 [N][32]
    const float* __restrict__ bias1,    // [64]
    const float* __restrict__ W_src, const float* __restrict__ a_src,
    const float* __restrict__ W_dst, const float* __restrict__ a_dst,
    unsigned* __restrict__ hb2, float* __restrict__ alpha_src2,
    float* __restrict__ alpha_dst2, int N) {
    constexpr int K = 64, PAD = K + 8;
    __shared__ unsigned short sBt[80 * PAD];
    __shared__ unsigned short sX[64 * PAD];
    int tid = threadIdx.x;

    stage_sBt<K>(sBt, W_src, a_src, W_dst, a_dst, tid);

    int wid = tid >> 6, lane = tid & 63;
    int blockbase = blockIdx.x * 64;
    float blane = bias1[lane];

    for (int i = 0; i < 16; ++i) {
        int node = blockbase + wid * 16 + i;
        float fv = 0.f;
        if (node < N)
            fv = agg_node(node, row_ptr, csr_src, alpha_src1, alpha_dst1, hb1,
                          blane, lane);
        sX[(wid * 16 + i) * PAD + lane] = bf16bits(fv);
    }
    __syncthreads();
    nt_mfma_body<K>(sBt, sX, blockbase, hb2, alpha_src2, alpha_dst2, N, tid);
}

// ---------------------------------------------------------------------------
// Dispatch 6: final aggregation (layer 2) -> fp32 output.
// ---------------------------------------------------------------------------
__global__ __launch_bounds__(256) void aggregate_out(
    const int* __restrict__ row_ptr, const int* __restrict__ csr_src,
    const float* __restrict__ alpha_src, const float* __restrict__ alpha_dst,
    const unsigned* __restrict__ hb, const float* __restrict__ bias,
    float* __restrict__ out, int N) {
    int wid = threadIdx.x >> 6, lane = threadIdx.x & 63;
    int node = blockIdx.x * 4 + wid;
    if (node >= N) return;
    float fv = agg_node(node, row_ptr, csr_src, alpha_src, alpha_dst, hb,
                        bias[lane], lane);
    out[(size_t)node * 64 + lane] = fv;
}

// ---------------------------------------------------------------------------
extern "C" void kernel_launch(void* const* d_in, const int* in_sizes, int n_in,
                              void* d_out, int out_size, void* d_ws, size_t ws_size,
                              hipStream_t stream) {
    const float* x      = (const float*)d_in[0];
    const int*   src    = (const int*)  d_in[1];
    const int*   dst    = (const int*)  d_in[2];
    const float* W1_src = (const float*)d_in[3];
    const float* W1_dst = (const float*)d_in[4];
    const float* a1_src = (const float*)d_in[5];
    const float* a1_dst = (const float*)d_in[6];
    const float* b1     = (const float*)d_in[7];
    const float* W2_src = (const float*)d_in[8];
    const float* W2_dst = (const float*)d_in[9];
    const float* a2_src = (const float*)d_in[10];
    const float* a2_dst = (const float*)d_in[11];
    const float* b2     = (const float*)d_in[12];
    float* out = (float*)d_out;

    const int N = in_sizes[0] / 128;
    const int E = in_sizes[1];
    const int NB = (N + 255) / 256;          // buckets (196)

    // workspace layout (256-byte aligned slices)
    char* ws = (char*)d_ws;
    size_t off = 0;
    auto alloc = [&](size_t bytes) {
        void* p = ws + off;
        off += (bytes + 255) & ~(size_t)255;
        return p;
    };
    unsigned* hbuf1   = (unsigned*)alloc((size_t)N * 32 * 4);  // packed bf16 h (L1)
    unsigned* hbuf2   = (unsigned*)alloc((size_t)N * 32 * 4);  // packed bf16 h (L2)
    float* alpha_s1   = (float*)alloc((size_t)N * 4);
    float* alpha_d1   = (float*)alloc((size_t)N * 4);
    float* alpha_s2   = (float*)alloc((size_t)N * 4);
    float* alpha_d2   = (float*)alloc((size_t)N * 4);
    int*   row_ptr    = (int*)  alloc((size_t)(N + 1) * 4);
    int*   csr_src    = (int*)  alloc((size_t)E * 4);
    int*   partials   = (int*)  alloc(NHB * 256 * 4);
    int*   bucket_base   = (int*)alloc(257 * 4);
    int*   bucket_cursor = (int*)alloc(256 * 4);
    unsigned* ebuf    = (unsigned*)alloc((size_t)E * 4);
    (void)ws_size; (void)NB;

    const int eb3  = (E + EPB - 1) / EPB;    // bucket_scatter blocks
    const int aggb = (N + 3) / 4;            // aggregate_out: 4 nodes/block
    const int ntb  = (N + 63) / 64;          // NT tiles (64 rows/block)

    // 1) NT layer-1 || histogram partials
    fused_nt1_hist<<<ntb + NHB, 256, 0, stream>>>(
        x, W1_src, a1_src, W1_dst, a1_dst, hbuf1, alpha_s1, alpha_d1, N,
        dst, partials, E, ntb);
    // 2) scan
    bucket_scan<<<1, 256, 0, stream>>>(partials, bucket_base, bucket_cursor);
    // 3) scatter into buckets
    bucket_scatter<<<eb3, 256, 0, stream>>>(src, dst, bucket_cursor, ebuf, E);
    // 4) per-bucket CSR finalize
    bucket_build<<<NB, 256, 0, stream>>>(ebuf, bucket_base, row_ptr, csr_src, N, E);
    // 5) agg layer-1 + NT layer-2 (h1 never leaves LDS)
    fused_agg_nt<<<ntb, 256, 0, stream>>>(
        row_ptr, csr_src, alpha_s1, alpha_d1, hbuf1, b1,
        W2_src, a2_src, W2_dst, a2_dst, hbuf2, alpha_s2, alpha_d2, N);
    // 6) final aggregation -> out
    aggregate_out<<<aggb, 256, 0, stream>>>(
        row_ptr, csr_src, alpha_s2, alpha_d2, hbuf2, b2, out, N);
}